// Round 4
// baseline (110.119 us; speedup 1.0000x reference)
//
#include <hip/hip_runtime.h>
#include <math.h>

namespace {

constexpr int   L      = 3750;
constexpr int   BLK    = 256;
constexpr int   CH     = 16;                  // chunk per thread, 64B aligned
constexpr int   NCHUNK = (L + CH - 1) / CH;   // 235 (last chunk has 6 real elems)
constexpr int   PADE   = NCHUNK * CH;         // 3760
constexpr float EPS    = 1e-5f;

__device__ __forceinline__ float frcp(float x)  { return __builtin_amdgcn_rcpf(x); }
__device__ __forceinline__ float fsqrt(float x) { return __builtin_amdgcn_sqrtf(x); }

__global__ __launch_bounds__(BLK, 6)
void preproc_kernel(const float* __restrict__ in, float* __restrict__ out) {
    // LDS: ONLY the prefix array (y-prefix, then t^2-prefix). No staging/bounce.
    __shared__ __align__(16) float sp[PADE];
    __shared__ float sred[8];    // wave partials: [0:4) sum, [4:8) sumsq

    const int tid  = threadIdx.x;
    const int lane = tid & 63;
    const int wave = tid >> 6;
    const size_t rowoff = (size_t)blockIdx.x * (size_t)L;
    const float* rin  = in  + rowoff;
    float*       rout = out + rowoff;

    const bool active = (tid < NCHUNK);
    const bool full   = (tid < NCHUNK - 1);   // 16 real elements
    const int  base   = tid * CH;

    // ---- 1. chunk -> registers (float2, 8B-aligned; pad zeros) ----
    float y[CH];
    #pragma unroll
    for (int j = 0; j < CH; ++j) y[j] = 0.f;
    if (full) {
        const float2* g = reinterpret_cast<const float2*>(rin + base);
        #pragma unroll
        for (int h = 0; h < CH / 2; ++h) {
            const float2 v = g[h];
            y[2*h] = v.x; y[2*h+1] = v.y;
        }
    } else if (active) {                       // tid 234: elems [3744,3750)
        const float2* g = reinterpret_cast<const float2*>(rin + base);
        #pragma unroll
        for (int h = 0; h < 3; ++h) {
            const float2 v = g[h];
            y[2*h] = v.x; y[2*h+1] = v.y;
        }
    }

    // ---- 2. block scan of (sum, sumsq) -> mean, var, zinv ----
    float cy = 0.f, cy2 = 0.f;
    #pragma unroll
    for (int j = 0; j < CH; ++j) { cy += y[j]; cy2 = fmaf(y[j], y[j], cy2); }
    float iy = cy, iy2 = cy2;
    #pragma unroll
    for (int d = 1; d < 64; d <<= 1) {
        const float u  = __shfl_up(iy,  (unsigned)d, 64);
        const float u2 = __shfl_up(iy2, (unsigned)d, 64);
        if (lane >= d) { iy += u; iy2 += u2; }
    }
    if (lane == 63) { sred[wave] = iy; sred[4 + wave] = iy2; }
    __syncthreads();                           // B1
    float woff = 0.f;
    #pragma unroll
    for (int w = 0; w < 4; ++w) if (w < wave) woff += sred[w];
    const float totY  = sred[0] + sred[1] + sred[2] + sred[3];
    const float totY2 = sred[4] + sred[5] + sred[6] + sred[7];
    const float mean  = totY * (1.f / (float)L);
    const float var   = (totY2 - totY * mean) * (1.f / (float)(L - 1));
    const float zinv  = frcp(fsqrt(var) + EPS);   // 1/(std+eps)

    // ---- 3. exclusive y-prefix -> sp (quad writes) ----
    if (active) {
        float run = woff + iy - cy;
        float4* q = reinterpret_cast<float4*>(sp + base);
        #pragma unroll
        for (int h = 0; h < CH / 4; ++h) {
            float4 w;
            w.x = run; run += y[4*h+0];
            w.y = run; run += y[4*h+1];
            w.z = run; run += y[4*h+2];
            w.w = run; run += y[4*h+3];
            q[h] = w;
        }
    }
    __syncthreads();                           // B2: y-prefix ready

    // ---- 4. t = z - MA(z) in place (interior: mean cancels) ----
    const float inv251  = 1.f / 251.f;
    const float zinv251 = zinv * inv251;
    if (active) {
        if (tid >= 8 && tid <= 225) {          // untruncated MA windows
            float d[CH];
            {   // lo side: P[base-125+j] = a[3+j], quads from base-128
                const float4* q = reinterpret_cast<const float4*>(sp + base - 128);
                float a[20];
                #pragma unroll
                for (int h = 0; h < 5; ++h) {
                    const float4 v = q[h];
                    a[4*h]=v.x; a[4*h+1]=v.y; a[4*h+2]=v.z; a[4*h+3]=v.w;
                }
                #pragma unroll
                for (int j = 0; j < CH; ++j) d[j] = -a[3 + j];
            }
            {   // hi side: P[base+126+j] = a[2+j], quads from base+124
                const float4* q = reinterpret_cast<const float4*>(sp + base + 124);
                float a[20];
                #pragma unroll
                for (int h = 0; h < 5; ++h) {
                    const float4 v = q[h];
                    a[4*h]=v.x; a[4*h+1]=v.y; a[4*h+2]=v.z; a[4*h+3]=v.w;
                }
                #pragma unroll
                for (int j = 0; j < CH; ++j) d[j] += a[2 + j];
            }
            #pragma unroll
            for (int j = 0; j < CH; ++j)
                y[j] = zinv * fmaf(d[j], -inv251, y[j]);   // zinv*(y - win/251)
        } else {                               // boundary: clamped + mean term
            #pragma unroll
            for (int j = 0; j < CH; ++j) {
                const int i = base + j;
                if (i < L) {
                    const int lo = (i > 125) ? i - 125 : 0;
                    const int hi = (i + 126 < L) ? i + 126 : L;
                    const float winY = sp[hi] - sp[lo] - (float)(hi - lo) * mean;
                    y[j] = (y[j] - mean) * zinv - winY * zinv251;
                } else {
                    y[j] = 0.f;
                }
            }
        }
    }

    // ---- 5. t^2 scan + exclusive prefix -> sp ----
    float ct = 0.f;
    #pragma unroll
    for (int j = 0; j < CH; ++j) ct = fmaf(y[j], y[j], ct);
    float it = ct;
    #pragma unroll
    for (int d = 1; d < 64; d <<= 1) {
        const float u = __shfl_up(it, (unsigned)d, 64);
        if (lane >= d) it += u;
    }
    if (lane == 63) sred[wave] = it;
    __syncthreads();                           // B3: window reads done, sred(B) ready
    float woff2 = 0.f;
    #pragma unroll
    for (int w = 0; w < 4; ++w) if (w < wave) woff2 += sred[w];
    if (active) {
        float run = woff2 + it - ct;
        float4* q = reinterpret_cast<float4*>(sp + base);
        #pragma unroll
        for (int h = 0; h < CH / 4; ++h) {
            float4 w;
            w.x = run; run = fmaf(y[4*h+0], y[4*h+0], run);
            w.y = run; run = fmaf(y[4*h+1], y[4*h+1], run);
            w.z = run; run = fmaf(y[4*h+2], y[4*h+2], run);
            w.w = run; run = fmaf(y[4*h+3], y[4*h+3], run);
            q[h] = w;
        }
    }
    __syncthreads();                           // B4: t^2-prefix ready

    // ---- 6. r = t / (sqrt(MV)+eps); store direct from regs ----
    const float inv501 = 1.f / 501.f;
    if (active) {
        if (tid >= 16 && tid <= 217) {         // untruncated MV windows
            float d[CH];
            {   // lo side: P[base-250+j] = a[2+j], quads from base-252
                const float4* q = reinterpret_cast<const float4*>(sp + base - 252);
                float a[20];
                #pragma unroll
                for (int h = 0; h < 5; ++h) {
                    const float4 v = q[h];
                    a[4*h]=v.x; a[4*h+1]=v.y; a[4*h+2]=v.z; a[4*h+3]=v.w;
                }
                #pragma unroll
                for (int j = 0; j < CH; ++j) d[j] = -a[2 + j];
            }
            {   // hi side: P[base+251+j] = a[3+j], quads from base+248
                const float4* q = reinterpret_cast<const float4*>(sp + base + 248);
                float a[20];
                #pragma unroll
                for (int h = 0; h < 5; ++h) {
                    const float4 v = q[h];
                    a[4*h]=v.x; a[4*h+1]=v.y; a[4*h+2]=v.z; a[4*h+3]=v.w;
                }
                #pragma unroll
                for (int j = 0; j < CH; ++j) d[j] += a[3 + j];
            }
            #pragma unroll
            for (int j = 0; j < CH; ++j) {
                float mv = d[j] * inv501;
                mv = fmaxf(mv, 0.f);
                y[j] = y[j] * frcp(fsqrt(mv) + EPS);
            }
        } else {                               // boundary: clamped
            #pragma unroll
            for (int j = 0; j < CH; ++j) {
                const int i = base + j;
                if (i < L) {
                    const int lo = (i > 250) ? i - 250 : 0;
                    const int hi = (i + 251 < L) ? i + 251 : L;
                    float mv = (sp[hi] - sp[lo]) * inv501;
                    mv = fmaxf(mv, 0.f);
                    y[j] = y[j] * frcp(fsqrt(mv) + EPS);
                }
            }
        }
        // direct coalesced-enough store (float2, full lines via L2 merge)
        float2* gout = reinterpret_cast<float2*>(rout + base);
        if (full) {
            #pragma unroll
            for (int h = 0; h < CH / 2; ++h) {
                float2 v; v.x = y[2*h]; v.y = y[2*h+1];
                gout[h] = v;
            }
        } else {
            #pragma unroll
            for (int h = 0; h < 3; ++h) {
                float2 v; v.x = y[2*h]; v.y = y[2*h+1];
                gout[h] = v;
            }
        }
    }
}

}  // namespace

extern "C" void kernel_launch(void* const* d_in, const int* in_sizes, int n_in,
                              void* d_out, int out_size, void* d_ws, size_t ws_size,
                              hipStream_t stream) {
    const float* x = (const float*)d_in[0];
    float* out = (float*)d_out;
    const int rows = in_sizes[0] / L;   // 8192
    preproc_kernel<<<rows, BLK, 0, stream>>>(x, out);
}

// Round 5
// 68.913 us; speedup vs baseline: 1.5979x; 1.5979x over previous
//
#include <hip/hip_runtime.h>
#include <math.h>

namespace {

constexpr int   L      = 3750;
constexpr int   BLK    = 256;
constexpr int   CH     = 16;                  // chunk per thread, 64B aligned
constexpr int   NCHUNK = (L + CH - 1) / CH;   // 235 (last chunk has 6 real elems)
constexpr int   NQUAD  = (NCHUNK * CH) / 4;   // 940 logical quads
constexpr int   PHYSQ  = 944;                 // swizzle range bound: (939|7)+1
constexpr float EPS    = 1e-5f;

__device__ __forceinline__ float frcp(float x)  { return __builtin_amdgcn_rcpf(x); }
__device__ __forceinline__ float fsqrt(float x) { return __builtin_amdgcn_sqrtf(x); }

// quad-level XOR swizzle: spreads lane-stride-4-quad patterns over all banks
__device__ __forceinline__ int swq(int g) { return g ^ ((g >> 3) & 7); }
// scalar access to logical float index f under the swizzle (boundary paths)
__device__ __forceinline__ float lds_at(const float* sp, int f) {
    return sp[(swq(f >> 2) << 2) | (f & 3)];
}

__global__ __launch_bounds__(BLK, 6)
void preproc_kernel(const float* __restrict__ in, float* __restrict__ out) {
    // LDS: ONLY the (swizzled) prefix array: y-prefix, then t^2-prefix.
    __shared__ __align__(16) float sp[PHYSQ * 4];
    __shared__ float sred[8];    // wave partials: [0:4) sum, [4:8) sumsq

    const int tid  = threadIdx.x;
    const int lane = tid & 63;
    const int wave = tid >> 6;
    const size_t rowoff = (size_t)blockIdx.x * (size_t)L;
    const float* rin  = in  + rowoff;
    float*       rout = out + rowoff;

    const bool active = (tid < NCHUNK);
    const bool full   = (tid < NCHUNK - 1);   // 16 real elements
    const int  base   = tid * CH;

    // ---- 1. chunk -> registers (float2, 8B-aligned rows; pad zeros) ----
    float y[CH];
    #pragma unroll
    for (int j = 0; j < CH; ++j) y[j] = 0.f;
    if (full) {
        const float2* g = reinterpret_cast<const float2*>(rin + base);
        #pragma unroll
        for (int h = 0; h < CH / 2; ++h) {
            const float2 v = g[h];
            y[2*h] = v.x; y[2*h+1] = v.y;
        }
    } else if (active) {                       // tid 234: elems [3744,3750)
        const float2* g = reinterpret_cast<const float2*>(rin + base);
        #pragma unroll
        for (int h = 0; h < 3; ++h) {
            const float2 v = g[h];
            y[2*h] = v.x; y[2*h+1] = v.y;
        }
    }

    // ---- 2. block scan of (sum, sumsq) -> mean, var, zinv ----
    float cy = 0.f, cy2 = 0.f;
    #pragma unroll
    for (int j = 0; j < CH; ++j) { cy += y[j]; cy2 = fmaf(y[j], y[j], cy2); }
    float iy = cy, iy2 = cy2;
    #pragma unroll
    for (int d = 1; d < 64; d <<= 1) {
        const float u  = __shfl_up(iy,  (unsigned)d, 64);
        const float u2 = __shfl_up(iy2, (unsigned)d, 64);
        if (lane >= d) { iy += u; iy2 += u2; }
    }
    if (lane == 63) { sred[wave] = iy; sred[4 + wave] = iy2; }
    __syncthreads();                           // B1
    float woff = 0.f;
    #pragma unroll
    for (int w = 0; w < 4; ++w) if (w < wave) woff += sred[w];
    const float totY  = sred[0] + sred[1] + sred[2] + sred[3];
    const float totY2 = sred[4] + sred[5] + sred[6] + sred[7];
    const float mean  = totY * (1.f / (float)L);
    const float var   = (totY2 - totY * mean) * (1.f / (float)(L - 1));
    const float zinv  = frcp(fsqrt(var) + EPS);   // 1/(std+eps)

    // ---- 3. exclusive y-prefix -> sp (swizzled quad writes) ----
    if (active) {
        float run = woff + iy - cy;
        float4* q4 = reinterpret_cast<float4*>(sp);
        const int gq = tid * 4;
        #pragma unroll
        for (int h = 0; h < CH / 4; ++h) {
            float4 w;
            w.x = run; run += y[4*h+0];
            w.y = run; run += y[4*h+1];
            w.z = run; run += y[4*h+2];
            w.w = run; run += y[4*h+3];
            q4[swq(gq + h)] = w;
        }
    }
    __syncthreads();                           // B2: y-prefix ready

    // ---- 4. t = z - MA(z) in place (interior: mean cancels) ----
    const float inv251  = 1.f / 251.f;
    const float zinv251 = zinv * inv251;
    if (active) {
        if (tid >= 8 && tid <= 225) {          // untruncated MA windows
            const float4* q4 = reinterpret_cast<const float4*>(sp);
            float d[CH];
            {   // lo side: P[base-125+j] = a[3+j], quads from quad 4t-32
                const int gl = tid * 4 - 32;
                float a[20];
                #pragma unroll
                for (int h = 0; h < 5; ++h) {
                    const float4 v = q4[swq(gl + h)];
                    a[4*h]=v.x; a[4*h+1]=v.y; a[4*h+2]=v.z; a[4*h+3]=v.w;
                }
                #pragma unroll
                for (int j = 0; j < CH; ++j) d[j] = -a[3 + j];
            }
            {   // hi side: P[base+126+j] = a[2+j], quads from quad 4t+31
                const int gh = tid * 4 + 31;
                float a[20];
                #pragma unroll
                for (int h = 0; h < 5; ++h) {
                    const float4 v = q4[swq(gh + h)];
                    a[4*h]=v.x; a[4*h+1]=v.y; a[4*h+2]=v.z; a[4*h+3]=v.w;
                }
                #pragma unroll
                for (int j = 0; j < CH; ++j) d[j] += a[2 + j];
            }
            #pragma unroll
            for (int j = 0; j < CH; ++j)
                y[j] = zinv * fmaf(d[j], -inv251, y[j]);   // zinv*(y - win/251)
        } else {                               // boundary: clamped + mean term
            #pragma unroll
            for (int j = 0; j < CH; ++j) {
                const int i = base + j;
                if (i < L) {
                    const int lo = (i > 125) ? i - 125 : 0;
                    const int hi = (i + 126 < L) ? i + 126 : L;
                    const float winY = lds_at(sp, hi) - lds_at(sp, lo)
                                       - (float)(hi - lo) * mean;
                    y[j] = (y[j] - mean) * zinv - winY * zinv251;
                } else {
                    y[j] = 0.f;
                }
            }
        }
    }

    // ---- 5. t^2 scan + exclusive prefix -> sp (swizzled) ----
    float ct = 0.f;
    #pragma unroll
    for (int j = 0; j < CH; ++j) ct = fmaf(y[j], y[j], ct);
    float it = ct;
    #pragma unroll
    for (int d = 1; d < 64; d <<= 1) {
        const float u = __shfl_up(it, (unsigned)d, 64);
        if (lane >= d) it += u;
    }
    if (lane == 63) sred[wave] = it;
    __syncthreads();                           // B3: window reads done, sred(B) ready
    float woff2 = 0.f;
    #pragma unroll
    for (int w = 0; w < 4; ++w) if (w < wave) woff2 += sred[w];
    if (active) {
        float run = woff2 + it - ct;
        float4* q4 = reinterpret_cast<float4*>(sp);
        const int gq = tid * 4;
        #pragma unroll
        for (int h = 0; h < CH / 4; ++h) {
            float4 w;
            w.x = run; run = fmaf(y[4*h+0], y[4*h+0], run);
            w.y = run; run = fmaf(y[4*h+1], y[4*h+1], run);
            w.z = run; run = fmaf(y[4*h+2], y[4*h+2], run);
            w.w = run; run = fmaf(y[4*h+3], y[4*h+3], run);
            q4[swq(gq + h)] = w;
        }
    }
    __syncthreads();                           // B4: t^2-prefix ready

    // ---- 6. r = t / (sqrt(MV)+eps); store direct from regs ----
    const float inv501 = 1.f / 501.f;
    if (active) {
        if (tid >= 16 && tid <= 217) {         // untruncated MV windows
            const float4* q4 = reinterpret_cast<const float4*>(sp);
            float d[CH];
            {   // lo side: P[base-250+j] = a[2+j], quads from quad 4t-63
                const int gl = tid * 4 - 63;
                float a[20];
                #pragma unroll
                for (int h = 0; h < 5; ++h) {
                    const float4 v = q4[swq(gl + h)];
                    a[4*h]=v.x; a[4*h+1]=v.y; a[4*h+2]=v.z; a[4*h+3]=v.w;
                }
                #pragma unroll
                for (int j = 0; j < CH; ++j) d[j] = -a[2 + j];
            }
            {   // hi side: P[base+251+j] = a[3+j], quads from quad 4t+62
                const int gh = tid * 4 + 62;
                float a[20];
                #pragma unroll
                for (int h = 0; h < 5; ++h) {
                    const float4 v = q4[swq(gh + h)];
                    a[4*h]=v.x; a[4*h+1]=v.y; a[4*h+2]=v.z; a[4*h+3]=v.w;
                }
                #pragma unroll
                for (int j = 0; j < CH; ++j) d[j] += a[3 + j];
            }
            #pragma unroll
            for (int j = 0; j < CH; ++j) {
                float mv = d[j] * inv501;
                mv = fmaxf(mv, 0.f);
                y[j] = y[j] * frcp(fsqrt(mv) + EPS);
            }
        } else {                               // boundary: clamped
            #pragma unroll
            for (int j = 0; j < CH; ++j) {
                const int i = base + j;
                if (i < L) {
                    const int lo = (i > 250) ? i - 250 : 0;
                    const int hi = (i + 251 < L) ? i + 251 : L;
                    float mv = (lds_at(sp, hi) - lds_at(sp, lo)) * inv501;
                    mv = fmaxf(mv, 0.f);
                    y[j] = y[j] * frcp(fsqrt(mv) + EPS);
                }
            }
        }
        // direct store (float2; rows are only 8B-aligned)
        float2* gout = reinterpret_cast<float2*>(rout + base);
        if (full) {
            #pragma unroll
            for (int h = 0; h < CH / 2; ++h) {
                float2 v; v.x = y[2*h]; v.y = y[2*h+1];
                gout[h] = v;
            }
        } else {
            #pragma unroll
            for (int h = 0; h < 3; ++h) {
                float2 v; v.x = y[2*h]; v.y = y[2*h+1];
                gout[h] = v;
            }
        }
    }
}

}  // namespace

extern "C" void kernel_launch(void* const* d_in, const int* in_sizes, int n_in,
                              void* d_out, int out_size, void* d_ws, size_t ws_size,
                              hipStream_t stream) {
    const float* x = (const float*)d_in[0];
    float* out = (float*)d_out;
    const int rows = in_sizes[0] / L;   // 8192
    preproc_kernel<<<rows, BLK, 0, stream>>>(x, out);
}

// Round 6
// 62.023 us; speedup vs baseline: 1.7755x; 1.1111x over previous
//
#include <hip/hip_runtime.h>
#include <math.h>

namespace {

constexpr int   L      = 3750;
constexpr int   NPAIR  = L / 2;               // 1875 float2 per row
constexpr int   BLK    = 256;
constexpr int   CH     = 16;                  // chunk per thread
constexpr int   NCHUNK = (L + CH - 1) / CH;   // 235 (last chunk has 6 real elems)
constexpr int   PHYSQ  = 944;                 // swizzled quad bound: swq(939)=942
constexpr float EPS    = 1e-5f;

__device__ __forceinline__ float frcp(float x)  { return __builtin_amdgcn_rcpf(x); }
__device__ __forceinline__ float fsqrt(float x) { return __builtin_amdgcn_sqrtf(x); }

// quad-level XOR swizzle: spreads lane-stride-4-quad patterns over all banks
__device__ __forceinline__ int swq(int g) { return g ^ ((g >> 3) & 7); }
// scalar access to logical float index f under the swizzle (boundary paths)
__device__ __forceinline__ float lds_at(const float* sp, int f) {
    return sp[(swq(f >> 2) << 2) | (f & 3)];
}

__global__ __launch_bounds__(BLK, 6)
void preproc_kernel(const float* __restrict__ in, float* __restrict__ out) {
    // ONE swizzled LDS array, reused: staging -> y-prefix -> t^2-prefix -> result
    __shared__ __align__(16) float sp[PHYSQ * 4];
    __shared__ float sred[8];    // wave partials: [0:4) sum, [4:8) sumsq

    const int tid  = threadIdx.x;
    const int lane = tid & 63;
    const int wave = tid >> 6;
    const size_t rowoff = (size_t)blockIdx.x * (size_t)L;
    const float* rin  = in  + rowoff;
    float*       rout = out + rowoff;

    const bool active = (tid < NCHUNK);
    const bool full   = (tid < NCHUNK - 1);   // 16 real elements
    const int  base   = tid * CH;

    // ---- 1. coalesced load -> swizzled LDS staging ----
    {
        const float2* rin2 = reinterpret_cast<const float2*>(rin);
        float2* sp2 = reinterpret_cast<float2*>(sp);
        for (int i = tid; i < NPAIR; i += BLK)
            sp2[(swq(i >> 1) << 1) | (i & 1)] = rin2[i];
    }
    __syncthreads();                           // B1: row staged

    // ---- 2. chunk -> registers (4 swizzled b128); zero pad tail ----
    float y[CH];
    if (active) {
        const float4* q4 = reinterpret_cast<const float4*>(sp);
        #pragma unroll
        for (int h = 0; h < CH / 4; ++h) {
            const float4 v = q4[swq(4 * tid + h)];
            y[4*h] = v.x; y[4*h+1] = v.y; y[4*h+2] = v.z; y[4*h+3] = v.w;
        }
        if (!full) {                           // tid 234: elems [3744,3750)
            #pragma unroll
            for (int j = 6; j < CH; ++j) y[j] = 0.f;
        }
    } else {
        #pragma unroll
        for (int j = 0; j < CH; ++j) y[j] = 0.f;
    }

    // ---- 3. block scan of (sum, sumsq) -> mean, var, zinv ----
    float cy = 0.f, cy2 = 0.f;
    #pragma unroll
    for (int j = 0; j < CH; ++j) { cy += y[j]; cy2 = fmaf(y[j], y[j], cy2); }
    float iy = cy, iy2 = cy2;
    #pragma unroll
    for (int d = 1; d < 64; d <<= 1) {
        const float u  = __shfl_up(iy,  (unsigned)d, 64);
        const float u2 = __shfl_up(iy2, (unsigned)d, 64);
        if (lane >= d) { iy += u; iy2 += u2; }
    }
    if (lane == 63) { sred[wave] = iy; sred[4 + wave] = iy2; }
    __syncthreads();                           // B2: sred(A) ready, chunk reads done
    float woff = 0.f;
    #pragma unroll
    for (int w = 0; w < 4; ++w) if (w < wave) woff += sred[w];
    const float totY  = sred[0] + sred[1] + sred[2] + sred[3];
    const float totY2 = sred[4] + sred[5] + sred[6] + sred[7];
    const float mean  = totY * (1.f / (float)L);
    const float var   = (totY2 - totY * mean) * (1.f / (float)(L - 1));
    const float zinv  = frcp(fsqrt(var) + EPS);   // 1/(std+eps)

    // ---- 4. exclusive y-prefix -> sp (swizzled quad writes) ----
    if (active) {
        float run = woff + iy - cy;
        float4* q4 = reinterpret_cast<float4*>(sp);
        const int gq = tid * 4;
        #pragma unroll
        for (int h = 0; h < CH / 4; ++h) {
            float4 w;
            w.x = run; run += y[4*h+0];
            w.y = run; run += y[4*h+1];
            w.z = run; run += y[4*h+2];
            w.w = run; run += y[4*h+3];
            q4[swq(gq + h)] = w;
        }
    }
    __syncthreads();                           // B3: y-prefix ready

    // ---- 5. t = z - MA(z) in place (interior: mean cancels) ----
    const float inv251  = 1.f / 251.f;
    const float zinv251 = zinv * inv251;
    if (active) {
        if (tid >= 8 && tid <= 225) {          // untruncated MA windows
            const float4* q4 = reinterpret_cast<const float4*>(sp);
            float d[CH];
            {   // lo side: P[base-125+j] = a[3+j], quads from quad 4t-32
                const int gl = tid * 4 - 32;
                float a[20];
                #pragma unroll
                for (int h = 0; h < 5; ++h) {
                    const float4 v = q4[swq(gl + h)];
                    a[4*h]=v.x; a[4*h+1]=v.y; a[4*h+2]=v.z; a[4*h+3]=v.w;
                }
                #pragma unroll
                for (int j = 0; j < CH; ++j) d[j] = -a[3 + j];
            }
            {   // hi side: P[base+126+j] = a[2+j], quads from quad 4t+31
                const int gh = tid * 4 + 31;
                float a[20];
                #pragma unroll
                for (int h = 0; h < 5; ++h) {
                    const float4 v = q4[swq(gh + h)];
                    a[4*h]=v.x; a[4*h+1]=v.y; a[4*h+2]=v.z; a[4*h+3]=v.w;
                }
                #pragma unroll
                for (int j = 0; j < CH; ++j) d[j] += a[2 + j];
            }
            #pragma unroll
            for (int j = 0; j < CH; ++j)
                y[j] = zinv * fmaf(d[j], -inv251, y[j]);   // zinv*(y - win/251)
        } else {                               // boundary: clamped + mean term
            #pragma unroll
            for (int j = 0; j < CH; ++j) {
                const int i = base + j;
                if (i < L) {
                    const int lo = (i > 125) ? i - 125 : 0;
                    const int hi = (i + 126 < L) ? i + 126 : L;
                    const float winY = lds_at(sp, hi) - lds_at(sp, lo)
                                       - (float)(hi - lo) * mean;
                    y[j] = (y[j] - mean) * zinv - winY * zinv251;
                } else {
                    y[j] = 0.f;
                }
            }
        }
    }

    // ---- 6. t^2 scan + exclusive prefix -> sp (swizzled) ----
    float ct = 0.f;
    #pragma unroll
    for (int j = 0; j < CH; ++j) ct = fmaf(y[j], y[j], ct);
    float it = ct;
    #pragma unroll
    for (int d = 1; d < 64; d <<= 1) {
        const float u = __shfl_up(it, (unsigned)d, 64);
        if (lane >= d) it += u;
    }
    if (lane == 63) sred[wave] = it;
    __syncthreads();                           // B4: window reads + sred(B) ready
    float woff2 = 0.f;
    #pragma unroll
    for (int w = 0; w < 4; ++w) if (w < wave) woff2 += sred[w];
    if (active) {
        float run = woff2 + it - ct;
        float4* q4 = reinterpret_cast<float4*>(sp);
        const int gq = tid * 4;
        #pragma unroll
        for (int h = 0; h < CH / 4; ++h) {
            float4 w;
            w.x = run; run = fmaf(y[4*h+0], y[4*h+0], run);
            w.y = run; run = fmaf(y[4*h+1], y[4*h+1], run);
            w.z = run; run = fmaf(y[4*h+2], y[4*h+2], run);
            w.w = run; run = fmaf(y[4*h+3], y[4*h+3], run);
            q4[swq(gq + h)] = w;
        }
    }
    __syncthreads();                           // B5: t^2-prefix ready

    // ---- 7. r = t / (sqrt(MV)+eps) into regs ----
    const float inv501 = 1.f / 501.f;
    if (active) {
        if (tid >= 16 && tid <= 217) {         // untruncated MV windows
            const float4* q4 = reinterpret_cast<const float4*>(sp);
            float d[CH];
            {   // lo side: P[base-250+j] = a[2+j], quads from quad 4t-63
                const int gl = tid * 4 - 63;
                float a[20];
                #pragma unroll
                for (int h = 0; h < 5; ++h) {
                    const float4 v = q4[swq(gl + h)];
                    a[4*h]=v.x; a[4*h+1]=v.y; a[4*h+2]=v.z; a[4*h+3]=v.w;
                }
                #pragma unroll
                for (int j = 0; j < CH; ++j) d[j] = -a[2 + j];
            }
            {   // hi side: P[base+251+j] = a[3+j], quads from quad 4t+62
                const int gh = tid * 4 + 62;
                float a[20];
                #pragma unroll
                for (int h = 0; h < 5; ++h) {
                    const float4 v = q4[swq(gh + h)];
                    a[4*h]=v.x; a[4*h+1]=v.y; a[4*h+2]=v.z; a[4*h+3]=v.w;
                }
                #pragma unroll
                for (int j = 0; j < CH; ++j) d[j] += a[3 + j];
            }
            #pragma unroll
            for (int j = 0; j < CH; ++j) {
                float mv = d[j] * inv501;
                mv = fmaxf(mv, 0.f);
                y[j] = y[j] * frcp(fsqrt(mv) + EPS);
            }
        } else {                               // boundary: clamped
            #pragma unroll
            for (int j = 0; j < CH; ++j) {
                const int i = base + j;
                if (i < L) {
                    const int lo = (i > 250) ? i - 250 : 0;
                    const int hi = (i + 251 < L) ? i + 251 : L;
                    float mv = (lds_at(sp, hi) - lds_at(sp, lo)) * inv501;
                    mv = fmaxf(mv, 0.f);
                    y[j] = y[j] * frcp(fsqrt(mv) + EPS);
                }
            }
        }
    }
    __syncthreads();                           // B6: all prefix reads done

    // ---- 8. r -> swizzled LDS, then coalesced store ----
    if (active) {
        float4* q4 = reinterpret_cast<float4*>(sp);
        const int gq = tid * 4;
        #pragma unroll
        for (int h = 0; h < CH / 4; ++h) {
            float4 v;
            v.x = y[4*h]; v.y = y[4*h+1]; v.z = y[4*h+2]; v.w = y[4*h+3];
            q4[swq(gq + h)] = v;
        }
    }
    __syncthreads();                           // B7: result staged
    {
        const float2* sp2 = reinterpret_cast<const float2*>(sp);
        float2* rout2 = reinterpret_cast<float2*>(rout);
        for (int i = tid; i < NPAIR; i += BLK)
            rout2[i] = sp2[(swq(i >> 1) << 1) | (i & 1)];
    }
}

}  // namespace

extern "C" void kernel_launch(void* const* d_in, const int* in_sizes, int n_in,
                              void* d_out, int out_size, void* d_ws, size_t ws_size,
                              hipStream_t stream) {
    const float* x = (const float*)d_in[0];
    float* out = (float*)d_out;
    const int rows = in_sizes[0] / L;   // 8192
    preproc_kernel<<<rows, BLK, 0, stream>>>(x, out);
}